// Round 7
// baseline (272.024 us; speedup 1.0000x reference)
//
#include <hip/hip_runtime.h>
#include <hip/hip_cooperative_groups.h>
#include <hip/hip_bf16.h>
#include <math.h>

namespace cg = cooperative_groups;

// Problem constants
#define BB 2
#define HH 64
#define WW 64
#define DIMC 128
#define NH 4
#define HD 32
#define KS 7
#define DIL 2
#define NPIX (BB * HH * WW)         // 8192 rows
#define NBLK 512
#define SCALE 0.17677669529663687f  // 32^-0.5

typedef short bf16x8 __attribute__((ext_vector_type(8)));
typedef float f32x4  __attribute__((ext_vector_type(4)));

__device__ __forceinline__ short bf16r(float f) {
    union { float f; unsigned u; } x; x.f = f;
    unsigned r = x.u + 0x7FFF + ((x.u >> 16) & 1);  // RNE
    return (short)(r >> 16);
}
__device__ __forceinline__ float uasf(unsigned u) {
    union { unsigned u; float f; } x; x.u = u; return x.f;
}

// NATTEN edge-index helper (L=64, K=7, dil=2, ns=3).
__device__ __forceinline__ void natten_idx(int i, int& s, int& p)
{
    if (i < 6) {                 // i - ns*dil < 0
        s = i & 1;
        p = 6 - (i >> 1);
    } else if (i >= 58) {        // i + ns*dil >= L  (L%dil==0 -> b=0 path)
        s = 50 + (i & 1);        // a + i%dil - K*dil
        p = (63 - i) >> 1;
    } else {
        s = i - 6;
        p = 3;
    }
}

// ---------------------------------------------------------------------------
// Fully fused cooperative kernel: prep-W | qkv | natten | out-proj.
// 512 blocks x 256 threads (= 8192 pixels x 16 threads).
// ---------------------------------------------------------------------------
__global__ __launch_bounds__(256, 4) void fused_natten(
    const float* __restrict__ q, const float* __restrict__ k,
    const float* __restrict__ v,
    const float* __restrict__ Wq, const float* __restrict__ Wk,
    const float* __restrict__ Wv, const float* __restrict__ Wo,
    const float* __restrict__ bq, const float* __restrict__ bk,
    const float* __restrict__ bv, const float* __restrict__ bo,
    const float* __restrict__ rpb,
    float* __restrict__ qh, short* __restrict__ khb, short* __restrict__ vhb,
    short* __restrict__ Wt, float* __restrict__ out)
{
    __shared__ short T[32][136];     // S0 transpose tile
    __shared__ short attS[16][136];  // S2->S3 att tile (padded)

    cg::grid_group grid = cg::this_grid();

    const int blk = blockIdx.x;
    const int t   = threadIdx.x;

    // ---------------- S0: W -> Wt bf16 [z][n][k] (16 blocks) ----------------
    if (blk < 16) {
        const int z  = blk >> 2;
        const int ks = blk & 3;
        const float* W = (z == 0) ? Wq : (z == 1) ? Wk : (z == 2) ? Wv : Wo;
        const float4* Wg = (const float4*)(W + ks * 32 * 128);

        float4 xv[4];
#pragma unroll
        for (int u = 0; u < 4; ++u) xv[u] = Wg[u * 256 + t];
#pragma unroll
        for (int u = 0; u < 4; ++u) {
            const int e = u * 256 + t;
            const int r = e >> 5;
            const int c = (e & 31) * 4;
            short4 s4;
            s4.x = bf16r(xv[u].x); s4.y = bf16r(xv[u].y);
            s4.z = bf16r(xv[u].z); s4.w = bf16r(xv[u].w);
            *(short4*)&T[r][c] = s4;
        }
        __syncthreads();
        const int c = t >> 1;
        const int h = (t & 1) * 16;
        bf16x8 lo, hi;
#pragma unroll
        for (int e = 0; e < 8; ++e) { lo[e] = T[h + e][c]; hi[e] = T[h + 8 + e][c]; }
        short* outp = Wt + z * 16384 + c * 128 + ks * 32 + h;
        *(bf16x8*)(outp)     = lo;
        *(bf16x8*)(outp + 8) = hi;
    }

    __threadfence();
    grid.sync();

    // ---------------- S1: QKV projection via MFMA (768 units, strided) ------
    for (int u = blk; u < 768; u += NBLK) {
        const int z  = u >> 8;
        const int bx = u & 255;
        const float* X    = (z == 0) ? q  : (z == 1) ? k  : v;
        const float* bias = (z == 0) ? bq : (z == 1) ? bk : bv;
        const short* Wz   = Wt + z * 16384;

        const int wv   = t >> 6;
        const int lane = t & 63;
        const int lr   = lane & 15;
        const int lg   = lane >> 4;
        const int row0 = bx * 32 + (wv & 1) * 16;
        const int col0 = (wv >> 1) * 64;

        bf16x8 bfr[16];
#pragma unroll
        for (int nt = 0; nt < 4; ++nt) {
            const short* wrow = Wz + (col0 + nt * 16 + lr) * 128 + lg * 8;
#pragma unroll
            for (int kk = 0; kk < 4; ++kk)
                bfr[nt * 4 + kk] = *(const bf16x8*)(wrow + kk * 32);
        }

        const float* xrow = X + (size_t)(row0 + lr) * 128 + lg * 8;
        bf16x8 a[4];
#pragma unroll
        for (int kk = 0; kk < 4; ++kk) {
            const float4 x0 = *(const float4*)(xrow + kk * 32);
            const float4 x1 = *(const float4*)(xrow + kk * 32 + 4);
            bf16x8 av;
            av[0] = bf16r(x0.x); av[1] = bf16r(x0.y);
            av[2] = bf16r(x0.z); av[3] = bf16r(x0.w);
            av[4] = bf16r(x1.x); av[5] = bf16r(x1.y);
            av[6] = bf16r(x1.z); av[7] = bf16r(x1.w);
            a[kk] = av;
        }

#pragma unroll
        for (int nt = 0; nt < 4; ++nt) {
            const int col = col0 + nt * 16 + lr;
            f32x4 acc = {0.f, 0.f, 0.f, 0.f};
#pragma unroll
            for (int kk = 0; kk < 4; ++kk)
                acc = __builtin_amdgcn_mfma_f32_16x16x32_bf16(a[kk], bfr[nt * 4 + kk], acc, 0, 0, 0);
            const float bc = bias[col];
            if (z == 0) {
#pragma unroll
                for (int jj = 0; jj < 4; ++jj)
                    qh[(size_t)(row0 + lg * 4 + jj) * 128 + col] = (acc[jj] + bc) * SCALE;
            } else {
                short* Yb = (z == 1) ? khb : vhb;
#pragma unroll
                for (int jj = 0; jj < 4; ++jj)
                    Yb[(size_t)(row0 + lg * 4 + jj) * 128 + col] = bf16r(acc[jj] + bc);
            }
        }
    }

    __threadfence();
    grid.sync();

    // ---------------- S2: neighborhood attention ---------------------------
    // 4 lanes per (pixel,head), 8 channels each; 16 pixels per block.
    {
        const int lane4 = t & 3;
        const int n  = (t >> 2) & 3;
        const int p  = t >> 4;            // 0..15
        const int g  = blk * 16 + p;      // < 8192
        const int j  = g & 63;
        const int i  = (g >> 6) & 63;
        const int b  = g >> 12;

        int si, pi0, sj, pj0;
        natten_idx(i, si, pi0);
        natten_idx(j, sj, pj0);

        const int coff = n * 32 + lane4 * 8;
        const size_t pixb = (size_t)(b * 4096 + i * 64 + j);
        const float4 q0 = *(const float4*)(qh + pixb * 128 + coff);
        const float4 q1 = *(const float4*)(qh + pixb * 128 + coff + 4);

        const float* rp = rpb + n * 169;

        float sc[49];
#pragma unroll
        for (int ki = 0; ki < 7; ++ki) {
            const int iy = si + 2 * ki;
            const size_t rowbase = ((size_t)(b * 4096 + iy * 64)) * 128 + coff;
#pragma unroll
            for (int kj = 0; kj < 7; ++kj) {
                const int ix = sj + 2 * kj;
                const uint4 kv = *(const uint4*)(khb + rowbase + (size_t)ix * 128);
                float d =      q0.x * uasf(kv.x << 16);
                d = fmaf(q0.y, uasf(kv.x & 0xFFFF0000u), d);
                d = fmaf(q0.z, uasf(kv.y << 16), d);
                d = fmaf(q0.w, uasf(kv.y & 0xFFFF0000u), d);
                d = fmaf(q1.x, uasf(kv.z << 16), d);
                d = fmaf(q1.y, uasf(kv.z & 0xFFFF0000u), d);
                d = fmaf(q1.z, uasf(kv.w << 16), d);
                d = fmaf(q1.w, uasf(kv.w & 0xFFFF0000u), d);
                sc[ki * 7 + kj] = d;
            }
        }

#pragma unroll
        for (int u = 0; u < 49; ++u) sc[u] += __shfl_xor(sc[u], 1);
#pragma unroll
        for (int u = 0; u < 49; ++u) sc[u] += __shfl_xor(sc[u], 2);

        float m0 = -1e30f, m1 = -1e30f, m2 = -1e30f, m3 = -1e30f;
#pragma unroll
        for (int u = 0; u < 49; ++u) {
            const int ki = u / 7, kj = u % 7;
            sc[u] += rp[(pi0 + ki) * 13 + (pj0 + kj)];
            if ((u & 3) == 0)      m0 = fmaxf(m0, sc[u]);
            else if ((u & 3) == 1) m1 = fmaxf(m1, sc[u]);
            else if ((u & 3) == 2) m2 = fmaxf(m2, sc[u]);
            else                   m3 = fmaxf(m3, sc[u]);
        }
        const float m = fmaxf(fmaxf(m0, m1), fmaxf(m2, m3));

        float l0 = 0.f, l1 = 0.f, l2 = 0.f, l3 = 0.f;
#pragma unroll
        for (int u = 0; u < 49; ++u) {
            const float pe = __expf(sc[u] - m);
            sc[u] = pe;
            if ((u & 3) == 0)      l0 += pe;
            else if ((u & 3) == 1) l1 += pe;
            else if ((u & 3) == 2) l2 += pe;
            else                   l3 += pe;
        }
        const float inv = 1.0f / ((l0 + l1) + (l2 + l3));

        float o[8] = {0.f, 0.f, 0.f, 0.f, 0.f, 0.f, 0.f, 0.f};
#pragma unroll
        for (int ki = 0; ki < 7; ++ki) {
            const int iy = si + 2 * ki;
            const size_t rowbase = ((size_t)(b * 4096 + iy * 64)) * 128 + coff;
#pragma unroll
            for (int kj = 0; kj < 7; ++kj) {
                const int ix = sj + 2 * kj;
                const uint4 vv = *(const uint4*)(vhb + rowbase + (size_t)ix * 128);
                const float pe = sc[ki * 7 + kj];
                o[0] = fmaf(pe, uasf(vv.x << 16),          o[0]);
                o[1] = fmaf(pe, uasf(vv.x & 0xFFFF0000u),  o[1]);
                o[2] = fmaf(pe, uasf(vv.y << 16),          o[2]);
                o[3] = fmaf(pe, uasf(vv.y & 0xFFFF0000u),  o[3]);
                o[4] = fmaf(pe, uasf(vv.z << 16),          o[4]);
                o[5] = fmaf(pe, uasf(vv.z & 0xFFFF0000u),  o[5]);
                o[6] = fmaf(pe, uasf(vv.w << 16),          o[6]);
                o[7] = fmaf(pe, uasf(vv.w & 0xFFFF0000u),  o[7]);
            }
        }

        bf16x8 ow;
#pragma unroll
        for (int e = 0; e < 8; ++e) ow[e] = bf16r(o[e] * inv);
        *(bf16x8*)&attS[p][coff] = ow;
    }

    __syncthreads();

    // ---------------- S3: out projection from LDS att tile ------------------
    {
        const int wv   = t >> 6;
        const int lane = t & 63;
        const int lr   = lane & 15;
        const int lg   = lane >> 4;
        const int col0 = wv * 32;
        const short* Wz = Wt + 3 * 16384;

        bf16x8 bfr[8];
#pragma unroll
        for (int nt = 0; nt < 2; ++nt) {
            const short* wrow = Wz + (col0 + nt * 16 + lr) * 128 + lg * 8;
#pragma unroll
            for (int kk = 0; kk < 4; ++kk)
                bfr[nt * 4 + kk] = *(const bf16x8*)(wrow + kk * 32);
        }
        bf16x8 a[4];
#pragma unroll
        for (int kk = 0; kk < 4; ++kk)
            a[kk] = *(const bf16x8*)&attS[lr][kk * 32 + lg * 8];

#pragma unroll
        for (int nt = 0; nt < 2; ++nt) {
            const int col = col0 + nt * 16 + lr;
            f32x4 acc = {0.f, 0.f, 0.f, 0.f};
#pragma unroll
            for (int kk = 0; kk < 4; ++kk)
                acc = __builtin_amdgcn_mfma_f32_16x16x32_bf16(a[kk], bfr[nt * 4 + kk], acc, 0, 0, 0);
            const float bc = bo[col];
#pragma unroll
            for (int jj = 0; jj < 4; ++jj)
                out[(size_t)(blk * 16 + lg * 4 + jj) * 128 + col] = acc[jj] + bc;
        }
    }
}

// ---------------------------------------------------------------------------
extern "C" void kernel_launch(void* const* d_in, const int* in_sizes, int n_in,
                              void* d_out, int out_size, void* d_ws, size_t ws_size,
                              hipStream_t stream)
{
    const float* q   = (const float*)d_in[0];
    const float* k   = (const float*)d_in[1];
    const float* v   = (const float*)d_in[2];
    const float* Wq  = (const float*)d_in[3];
    const float* bq  = (const float*)d_in[4];
    const float* Wk  = (const float*)d_in[5];
    const float* bk  = (const float*)d_in[6];
    const float* Wv  = (const float*)d_in[7];
    const float* bv  = (const float*)d_in[8];
    const float* rpb = (const float*)d_in[9];
    const float* Wo  = (const float*)d_in[10];
    const float* bo  = (const float*)d_in[11];

    float* ws   = (float*)d_ws;
    float* qh   = ws;                                   // f32 [8192][128]  (4 MB)
    short* khb  = (short*)(ws + (size_t)NPIX * 128);    // bf16 [8192][128] (2 MB)
    short* vhb  = khb + (size_t)NPIX * 128;             // bf16 (2 MB)
    short* Wt   = vhb + (size_t)NPIX * 128;             // bf16 [4][128][128] (128 KB)
    float* out  = (float*)d_out;

    void* args[] = {
        (void*)&q, (void*)&k, (void*)&v,
        (void*)&Wq, (void*)&Wk, (void*)&Wv, (void*)&Wo,
        (void*)&bq, (void*)&bk, (void*)&bv, (void*)&bo,
        (void*)&rpb, (void*)&qh, (void*)&khb, (void*)&vhb,
        (void*)&Wt, (void*)&out
    };
    hipLaunchCooperativeKernel((void*)fused_natten, dim3(NBLK), dim3(256),
                               args, 0, stream);
}

// Round 8
// 36.637 us; speedup vs baseline: 7.4248x; 7.4248x over previous
//
#include <hip/hip_runtime.h>
#include <hip/hip_bf16.h>
#include <math.h>

// Problem constants
#define BB 2
#define HH 64
#define WW 64
#define DIMC 128
#define NH 4
#define HD 32
#define KS 7
#define DIL 2
#define NPIX (BB * HH * WW)         // 8192 rows
#define SCALE 0.17677669529663687f  // 32^-0.5

typedef short bf16x8 __attribute__((ext_vector_type(8)));
typedef float f32x4  __attribute__((ext_vector_type(4)));

__device__ __forceinline__ short bf16r(float f) {
    union { float f; unsigned u; } x; x.f = f;
    unsigned r = x.u + 0x7FFF + ((x.u >> 16) & 1);  // RNE
    return (short)(r >> 16);
}
__device__ __forceinline__ float uasf(unsigned u) {
    union { unsigned u; float f; } x; x.u = u; return x.f;
}

// ---------------------------------------------------------------------------
// prep_w: W f32 [128][128] (row=k,col=n) -> Wt bf16 [z][n][k] (transposed).
// 16 blocks: z = blk>>2 (Wq,Wk,Wv,Wo), ks = blk&3 (32-row k-slice).
// ---------------------------------------------------------------------------
__global__ __launch_bounds__(256) void prep_w(
    const float* __restrict__ Wq, const float* __restrict__ Wk,
    const float* __restrict__ Wv, const float* __restrict__ Wo,
    short* __restrict__ Wt)
{
    const int z  = blockIdx.x >> 2;
    const int ks = blockIdx.x & 3;
    const float* W = (z == 0) ? Wq : (z == 1) ? Wk : (z == 2) ? Wv : Wo;

    __shared__ short T[32][136];
    const int t = threadIdx.x;
    const float4* Wg = (const float4*)(W + ks * 32 * 128);

    float4 xv[4];
#pragma unroll
    for (int u = 0; u < 4; ++u) xv[u] = Wg[u * 256 + t];
#pragma unroll
    for (int u = 0; u < 4; ++u) {
        const int e = u * 256 + t;
        const int r = e >> 5;
        const int c = (e & 31) * 4;
        short4 s4;
        s4.x = bf16r(xv[u].x); s4.y = bf16r(xv[u].y);
        s4.z = bf16r(xv[u].z); s4.w = bf16r(xv[u].w);
        *(short4*)&T[r][c] = s4;
    }
    __syncthreads();

    const int c = t >> 1;
    const int h = (t & 1) * 16;
    bf16x8 lo, hi;
#pragma unroll
    for (int i = 0; i < 8; ++i) { lo[i] = T[h + i][c]; hi[i] = T[h + 8 + i][c]; }
    short* outp = Wt + z * 16384 + c * 128 + ks * 32 + h;
    *(bf16x8*)(outp)     = lo;
    *(bf16x8*)(outp + 8) = hi;
}

// ---------------------------------------------------------------------------
// qkv_mfma (R5, known-good): Y = (X @ W + b) * scale via mfma 16x16x32 bf16.
// Block = 32 rows, 4 waves; wave = 16 rows x 64 cols; 16 B-frags preloaded.
// ---------------------------------------------------------------------------
__global__ __launch_bounds__(256) void qkv_mfma(
    const float* __restrict__ q, const float* __restrict__ k,
    const float* __restrict__ v, const short* __restrict__ Wt,
    const float* __restrict__ bq, const float* __restrict__ bk,
    const float* __restrict__ bv,
    float* __restrict__ qh, short* __restrict__ khb, short* __restrict__ vhb)
{
    const int z = blockIdx.y;
    const float* X    = (z == 0) ? q  : (z == 1) ? k  : v;
    const float* bias = (z == 0) ? bq : (z == 1) ? bk : bv;
    const short* Wz   = Wt + z * 16384;

    const int t    = threadIdx.x;
    const int wv   = t >> 6;
    const int lane = t & 63;
    const int lr   = lane & 15;
    const int lg   = lane >> 4;
    const int row0 = blockIdx.x * 32 + (wv & 1) * 16;
    const int col0 = (wv >> 1) * 64;

    bf16x8 bfr[16];
#pragma unroll
    for (int nt = 0; nt < 4; ++nt) {
        const short* wrow = Wz + (col0 + nt * 16 + lr) * 128 + lg * 8;
#pragma unroll
        for (int kk = 0; kk < 4; ++kk)
            bfr[nt * 4 + kk] = *(const bf16x8*)(wrow + kk * 32);
    }

    const float* xrow = X + (size_t)(row0 + lr) * 128 + lg * 8;
    bf16x8 a[4];
#pragma unroll
    for (int kk = 0; kk < 4; ++kk) {
        const float4 x0 = *(const float4*)(xrow + kk * 32);
        const float4 x1 = *(const float4*)(xrow + kk * 32 + 4);
        bf16x8 av;
        av[0] = bf16r(x0.x); av[1] = bf16r(x0.y);
        av[2] = bf16r(x0.z); av[3] = bf16r(x0.w);
        av[4] = bf16r(x1.x); av[5] = bf16r(x1.y);
        av[6] = bf16r(x1.z); av[7] = bf16r(x1.w);
        a[kk] = av;
    }

#pragma unroll
    for (int nt = 0; nt < 4; ++nt) {
        const int col = col0 + nt * 16 + lr;
        f32x4 acc = {0.f, 0.f, 0.f, 0.f};
#pragma unroll
        for (int kk = 0; kk < 4; ++kk)
            acc = __builtin_amdgcn_mfma_f32_16x16x32_bf16(a[kk], bfr[nt * 4 + kk], acc, 0, 0, 0);
        const float bc = bias[col];
        if (z == 0) {
#pragma unroll
            for (int jj = 0; jj < 4; ++jj)
                qh[(size_t)(row0 + lg * 4 + jj) * 128 + col] = (acc[jj] + bc) * SCALE;
        } else {
            short* Yb = (z == 1) ? khb : vhb;
#pragma unroll
            for (int jj = 0; jj < 4; ++jj)
                Yb[(size_t)(row0 + lg * 4 + jj) * 128 + col] = bf16r(acc[jj] + bc);
        }
    }
}

// NATTEN edge-index helper (L=64, K=7, dil=2, ns=3).
__device__ __forceinline__ void natten_idx(int i, int& s, int& p)
{
    if (i < 6) {                 // i - ns*dil < 0
        s = i & 1;
        p = 6 - (i >> 1);
    } else if (i >= 58) {        // i + ns*dil >= L  (L%dil==0 -> b=0 path)
        s = 50 + (i & 1);        // a + i%dil - K*dil
        p = (63 - i) >> 1;
    } else {
        s = i - 6;
        p = 3;
    }
}

// ---------------------------------------------------------------------------
// natten_out: attention (4 lanes per (px,head), uint4 K/V loads) -> LDS att
// tile -> out projection via MFMA. 512 blocks x 256 thr (16 px/block).
// XCD-swizzled work id: 64 consecutive tiles (16 image rows) per XCD.
// ---------------------------------------------------------------------------
__global__ __launch_bounds__(256) void natten_out(
    const float* __restrict__ qh, const short* __restrict__ khb,
    const short* __restrict__ vhb, const float* __restrict__ rpb,
    const short* __restrict__ Wt, const float* __restrict__ bo,
    float* __restrict__ out)
{
    __shared__ short attS[16][136];

    const int blk  = blockIdx.x;
    const int work = (blk & 7) * 64 + (blk >> 3);   // bijective (512 = 8*64)
    const int t    = threadIdx.x;

    // ---------------- S2: neighborhood attention ----------------------------
    {
        const int lane4 = t & 3;
        const int n  = (t >> 2) & 3;
        const int p  = t >> 4;            // 0..15
        const int g  = work * 16 + p;     // < 8192
        const int j  = g & 63;
        const int i  = (g >> 6) & 63;
        const int b  = g >> 12;

        int si, pi0, sj, pj0;
        natten_idx(i, si, pi0);
        natten_idx(j, sj, pj0);

        const int coff = n * 32 + lane4 * 8;
        const size_t pixb = (size_t)(b * 4096 + i * 64 + j);
        const float4 q0 = *(const float4*)(qh + pixb * 128 + coff);
        const float4 q1 = *(const float4*)(qh + pixb * 128 + coff + 4);

        const float* rp = rpb + n * 169;

        float sc[49];
#pragma unroll
        for (int ki = 0; ki < 7; ++ki) {
            const int iy = si + 2 * ki;
            const size_t rowbase = ((size_t)(b * 4096 + iy * 64)) * 128 + coff;
#pragma unroll
            for (int kj = 0; kj < 7; ++kj) {
                const int ix = sj + 2 * kj;
                const uint4 kv = *(const uint4*)(khb + rowbase + (size_t)ix * 128);
                float d =      q0.x * uasf(kv.x << 16);
                d = fmaf(q0.y, uasf(kv.x & 0xFFFF0000u), d);
                d = fmaf(q0.z, uasf(kv.y << 16), d);
                d = fmaf(q0.w, uasf(kv.y & 0xFFFF0000u), d);
                d = fmaf(q1.x, uasf(kv.z << 16), d);
                d = fmaf(q1.y, uasf(kv.z & 0xFFFF0000u), d);
                d = fmaf(q1.z, uasf(kv.w << 16), d);
                d = fmaf(q1.w, uasf(kv.w & 0xFFFF0000u), d);
                sc[ki * 7 + kj] = d;
            }
        }

#pragma unroll
        for (int u = 0; u < 49; ++u) sc[u] += __shfl_xor(sc[u], 1);
#pragma unroll
        for (int u = 0; u < 49; ++u) sc[u] += __shfl_xor(sc[u], 2);

        float m0 = -1e30f, m1 = -1e30f, m2 = -1e30f, m3 = -1e30f;
#pragma unroll
        for (int u = 0; u < 49; ++u) {
            const int ki = u / 7, kj = u % 7;
            sc[u] += rp[(pi0 + ki) * 13 + (pj0 + kj)];
            if ((u & 3) == 0)      m0 = fmaxf(m0, sc[u]);
            else if ((u & 3) == 1) m1 = fmaxf(m1, sc[u]);
            else if ((u & 3) == 2) m2 = fmaxf(m2, sc[u]);
            else                   m3 = fmaxf(m3, sc[u]);
        }
        const float m = fmaxf(fmaxf(m0, m1), fmaxf(m2, m3));

        float l0 = 0.f, l1 = 0.f, l2 = 0.f, l3 = 0.f;
#pragma unroll
        for (int u = 0; u < 49; ++u) {
            const float pe = __expf(sc[u] - m);
            sc[u] = pe;
            if ((u & 3) == 0)      l0 += pe;
            else if ((u & 3) == 1) l1 += pe;
            else if ((u & 3) == 2) l2 += pe;
            else                   l3 += pe;
        }
        const float inv = 1.0f / ((l0 + l1) + (l2 + l3));

        float o[8] = {0.f, 0.f, 0.f, 0.f, 0.f, 0.f, 0.f, 0.f};
#pragma unroll
        for (int ki = 0; ki < 7; ++ki) {
            const int iy = si + 2 * ki;
            const size_t rowbase = ((size_t)(b * 4096 + iy * 64)) * 128 + coff;
#pragma unroll
            for (int kj = 0; kj < 7; ++kj) {
                const int ix = sj + 2 * kj;
                const uint4 vv = *(const uint4*)(vhb + rowbase + (size_t)ix * 128);
                const float pe = sc[ki * 7 + kj];
                o[0] = fmaf(pe, uasf(vv.x << 16),          o[0]);
                o[1] = fmaf(pe, uasf(vv.x & 0xFFFF0000u),  o[1]);
                o[2] = fmaf(pe, uasf(vv.y << 16),          o[2]);
                o[3] = fmaf(pe, uasf(vv.y & 0xFFFF0000u),  o[3]);
                o[4] = fmaf(pe, uasf(vv.z << 16),          o[4]);
                o[5] = fmaf(pe, uasf(vv.z & 0xFFFF0000u),  o[5]);
                o[6] = fmaf(pe, uasf(vv.w << 16),          o[6]);
                o[7] = fmaf(pe, uasf(vv.w & 0xFFFF0000u),  o[7]);
            }
        }

        bf16x8 ow;
#pragma unroll
        for (int e = 0; e < 8; ++e) ow[e] = bf16r(o[e] * inv);
        *(bf16x8*)&attS[p][coff] = ow;
    }

    __syncthreads();

    // ---------------- S3: out projection from LDS att tile ------------------
    {
        const int wv   = t >> 6;
        const int lane = t & 63;
        const int lr   = lane & 15;
        const int lg   = lane >> 4;
        const int col0 = wv * 32;
        const short* Wz = Wt + 3 * 16384;

        bf16x8 bfr[8];
#pragma unroll
        for (int nt = 0; nt < 2; ++nt) {
            const short* wrow = Wz + (col0 + nt * 16 + lr) * 128 + lg * 8;
#pragma unroll
            for (int kk = 0; kk < 4; ++kk)
                bfr[nt * 4 + kk] = *(const bf16x8*)(wrow + kk * 32);
        }
        bf16x8 a[4];
#pragma unroll
        for (int kk = 0; kk < 4; ++kk)
            a[kk] = *(const bf16x8*)&attS[lr][kk * 32 + lg * 8];

#pragma unroll
        for (int nt = 0; nt < 2; ++nt) {
            const int col = col0 + nt * 16 + lr;
            f32x4 acc = {0.f, 0.f, 0.f, 0.f};
#pragma unroll
            for (int kk = 0; kk < 4; ++kk)
                acc = __builtin_amdgcn_mfma_f32_16x16x32_bf16(a[kk], bfr[nt * 4 + kk], acc, 0, 0, 0);
            const float bc = bo[col];
#pragma unroll
            for (int jj = 0; jj < 4; ++jj)
                out[(size_t)(work * 16 + lg * 4 + jj) * 128 + col] = acc[jj] + bc;
        }
    }
}

// ---------------------------------------------------------------------------
extern "C" void kernel_launch(void* const* d_in, const int* in_sizes, int n_in,
                              void* d_out, int out_size, void* d_ws, size_t ws_size,
                              hipStream_t stream)
{
    const float* q   = (const float*)d_in[0];
    const float* k   = (const float*)d_in[1];
    const float* v   = (const float*)d_in[2];
    const float* Wq  = (const float*)d_in[3];
    const float* bq  = (const float*)d_in[4];
    const float* Wk  = (const float*)d_in[5];
    const float* bk  = (const float*)d_in[6];
    const float* Wv  = (const float*)d_in[7];
    const float* bv  = (const float*)d_in[8];
    const float* rpb = (const float*)d_in[9];
    const float* Wo  = (const float*)d_in[10];
    const float* bo  = (const float*)d_in[11];

    float* ws   = (float*)d_ws;
    float* qh   = ws;                                   // f32 [8192][128]  (4 MB)
    short* khb  = (short*)(ws + (size_t)NPIX * 128);    // bf16 [8192][128] (2 MB)
    short* vhb  = khb + (size_t)NPIX * 128;             // bf16 (2 MB)
    short* Wt   = vhb + (size_t)NPIX * 128;             // bf16 [4][128][128] (128 KB)
    float* out  = (float*)d_out;

    hipLaunchKernelGGL(prep_w, dim3(16), dim3(256), 0, stream, Wq, Wk, Wv, Wo, Wt);

    hipLaunchKernelGGL(qkv_mfma, dim3(256, 3), dim3(256), 0, stream,
                       q, k, v, Wt, bq, bk, bv, qh, khb, vhb);

    hipLaunchKernelGGL(natten_out, dim3(512), dim3(256), 0, stream,
                       qh, khb, vhb, rpb, Wt, bo, out);
}

// Round 9
// 35.200 us; speedup vs baseline: 7.7279x; 1.0408x over previous
//
#include <hip/hip_runtime.h>
#include <hip/hip_bf16.h>
#include <math.h>

// Problem constants
#define BB 2
#define HH 64
#define WW 64
#define DIMC 128
#define NH 4
#define HD 32
#define KS 7
#define DIL 2
#define NPIX (BB * HH * WW)         // 8192 rows
#define SCALE 0.17677669529663687f  // 32^-0.5

typedef short bf16x8 __attribute__((ext_vector_type(8)));
typedef float f32x4  __attribute__((ext_vector_type(4)));

__device__ __forceinline__ short bf16r(float f) {
    union { float f; unsigned u; } x; x.f = f;
    unsigned r = x.u + 0x7FFF + ((x.u >> 16) & 1);  // RNE
    return (short)(r >> 16);
}
__device__ __forceinline__ float uasf(unsigned u) {
    union { unsigned u; float f; } x; x.u = u; return x.f;
}

// ---------------------------------------------------------------------------
// prep_w (R5, known-good): W f32 [128][128] -> Wt bf16 [z][n][k] transposed.
// ---------------------------------------------------------------------------
__global__ __launch_bounds__(256) void prep_w(
    const float* __restrict__ Wq, const float* __restrict__ Wk,
    const float* __restrict__ Wv, const float* __restrict__ Wo,
    short* __restrict__ Wt)
{
    const int z  = blockIdx.x >> 2;
    const int ks = blockIdx.x & 3;
    const float* W = (z == 0) ? Wq : (z == 1) ? Wk : (z == 2) ? Wv : Wo;

    __shared__ short T[32][136];
    const int t = threadIdx.x;
    const float4* Wg = (const float4*)(W + ks * 32 * 128);

    float4 xv[4];
#pragma unroll
    for (int u = 0; u < 4; ++u) xv[u] = Wg[u * 256 + t];
#pragma unroll
    for (int u = 0; u < 4; ++u) {
        const int e = u * 256 + t;
        const int r = e >> 5;
        const int c = (e & 31) * 4;
        short4 s4;
        s4.x = bf16r(xv[u].x); s4.y = bf16r(xv[u].y);
        s4.z = bf16r(xv[u].z); s4.w = bf16r(xv[u].w);
        *(short4*)&T[r][c] = s4;
    }
    __syncthreads();

    const int c = t >> 1;
    const int h = (t & 1) * 16;
    bf16x8 lo, hi;
#pragma unroll
    for (int i = 0; i < 8; ++i) { lo[i] = T[h + i][c]; hi[i] = T[h + 8 + i][c]; }
    short* outp = Wt + z * 16384 + c * 128 + ks * 32 + h;
    *(bf16x8*)(outp)     = lo;
    *(bf16x8*)(outp + 8) = hi;
}

// ---------------------------------------------------------------------------
// qkv_mfma (R5, known-good): Y = (X @ W + b) * scale via mfma 16x16x32 bf16.
// ---------------------------------------------------------------------------
__global__ __launch_bounds__(256) void qkv_mfma(
    const float* __restrict__ q, const float* __restrict__ k,
    const float* __restrict__ v, const short* __restrict__ Wt,
    const float* __restrict__ bq, const float* __restrict__ bk,
    const float* __restrict__ bv,
    float* __restrict__ qh, short* __restrict__ khb, short* __restrict__ vhb)
{
    const int z = blockIdx.y;
    const float* X    = (z == 0) ? q  : (z == 1) ? k  : v;
    const float* bias = (z == 0) ? bq : (z == 1) ? bk : bv;
    const short* Wz   = Wt + z * 16384;

    const int t    = threadIdx.x;
    const int wv   = t >> 6;
    const int lane = t & 63;
    const int lr   = lane & 15;
    const int lg   = lane >> 4;
    const int row0 = blockIdx.x * 32 + (wv & 1) * 16;
    const int col0 = (wv >> 1) * 64;

    bf16x8 bfr[16];
#pragma unroll
    for (int nt = 0; nt < 4; ++nt) {
        const short* wrow = Wz + (col0 + nt * 16 + lr) * 128 + lg * 8;
#pragma unroll
        for (int kk = 0; kk < 4; ++kk)
            bfr[nt * 4 + kk] = *(const bf16x8*)(wrow + kk * 32);
    }

    const float* xrow = X + (size_t)(row0 + lr) * 128 + lg * 8;
    bf16x8 a[4];
#pragma unroll
    for (int kk = 0; kk < 4; ++kk) {
        const float4 x0 = *(const float4*)(xrow + kk * 32);
        const float4 x1 = *(const float4*)(xrow + kk * 32 + 4);
        bf16x8 av;
        av[0] = bf16r(x0.x); av[1] = bf16r(x0.y);
        av[2] = bf16r(x0.z); av[3] = bf16r(x0.w);
        av[4] = bf16r(x1.x); av[5] = bf16r(x1.y);
        av[6] = bf16r(x1.z); av[7] = bf16r(x1.w);
        a[kk] = av;
    }

#pragma unroll
    for (int nt = 0; nt < 4; ++nt) {
        const int col = col0 + nt * 16 + lr;
        f32x4 acc = {0.f, 0.f, 0.f, 0.f};
#pragma unroll
        for (int kk = 0; kk < 4; ++kk)
            acc = __builtin_amdgcn_mfma_f32_16x16x32_bf16(a[kk], bfr[nt * 4 + kk], acc, 0, 0, 0);
        const float bc = bias[col];
        if (z == 0) {
#pragma unroll
            for (int jj = 0; jj < 4; ++jj)
                qh[(size_t)(row0 + lg * 4 + jj) * 128 + col] = (acc[jj] + bc) * SCALE;
        } else {
            short* Yb = (z == 1) ? khb : vhb;
#pragma unroll
            for (int jj = 0; jj < 4; ++jj)
                Yb[(size_t)(row0 + lg * 4 + jj) * 128 + col] = bf16r(acc[jj] + bc);
        }
    }
}

// NATTEN edge-index helper (L=64, K=7, dil=2, ns=3).
__device__ __forceinline__ void natten_idx(int i, int& s, int& p)
{
    if (i < 6) {                 // i - ns*dil < 0
        s = i & 1;
        p = 6 - (i >> 1);
    } else if (i >= 58) {        // i + ns*dil >= L  (L%dil==0 -> b=0 path)
        s = 50 + (i & 1);        // a + i%dil - K*dil
        p = (63 - i) >> 1;
    } else {
        s = i - 6;
        p = 3;
    }
}

// ---------------------------------------------------------------------------
// natten_out: row-grouped ONLINE softmax attention (d[7] live, no sc[49] ->
// no spill) -> LDS att tile -> out projection via MFMA.
// 512 blocks x 256 thr; 4 lanes per (px,head); XCD-swizzled work id.
// ---------------------------------------------------------------------------
__global__ __launch_bounds__(256) void natten_out(
    const float* __restrict__ qh, const short* __restrict__ khb,
    const short* __restrict__ vhb, const float* __restrict__ rpb,
    const short* __restrict__ Wt, const float* __restrict__ bo,
    float* __restrict__ out)
{
    __shared__ short attS[16][136];

    const int blk  = blockIdx.x;
    const int work = (blk & 7) * 64 + (blk >> 3);   // bijective (512 = 8*64)
    const int t    = threadIdx.x;

    // ---------------- S2: neighborhood attention (online, grouped) ----------
    {
        const int lane4 = t & 3;
        const int n  = (t >> 2) & 3;
        const int p  = t >> 4;            // 0..15
        const int g  = work * 16 + p;     // < 8192
        const int j  = g & 63;
        const int i  = (g >> 6) & 63;
        const int b  = g >> 12;

        int si, pi0, sj, pj0;
        natten_idx(i, si, pi0);
        natten_idx(j, sj, pj0);

        const int coff = n * 32 + lane4 * 8;
        const size_t pixb = (size_t)(b * 4096 + i * 64 + j);
        const float4 q0 = *(const float4*)(qh + pixb * 128 + coff);
        const float4 q1 = *(const float4*)(qh + pixb * 128 + coff + 4);

        const float* rp = rpb + n * 169;

        float m = -1e30f, l = 0.0f;
        float o[8] = {0.f, 0.f, 0.f, 0.f, 0.f, 0.f, 0.f, 0.f};

#pragma unroll
        for (int ki = 0; ki < 7; ++ki) {
            const int iy = si + 2 * ki;
            const size_t rowbase = ((size_t)(b * 4096 + iy * 64)) * 128 + coff;
            const float* rrow = rp + (pi0 + ki) * 13 + pj0;

            // 7 independent K loads + dots
            float d[7];
#pragma unroll
            for (int kj = 0; kj < 7; ++kj) {
                const int ix = sj + 2 * kj;
                const uint4 kv = *(const uint4*)(khb + rowbase + (size_t)ix * 128);
                float dd =      q0.x * uasf(kv.x << 16);
                dd = fmaf(q0.y, uasf(kv.x & 0xFFFF0000u), dd);
                dd = fmaf(q0.z, uasf(kv.y << 16), dd);
                dd = fmaf(q0.w, uasf(kv.y & 0xFFFF0000u), dd);
                dd = fmaf(q1.x, uasf(kv.z << 16), dd);
                dd = fmaf(q1.y, uasf(kv.z & 0xFFFF0000u), dd);
                dd = fmaf(q1.z, uasf(kv.w << 16), dd);
                dd = fmaf(q1.w, uasf(kv.w & 0xFFFF0000u), dd);
                d[kj] = dd;
            }
#pragma unroll
            for (int kj = 0; kj < 7; ++kj) d[kj] += __shfl_xor(d[kj], 1);
#pragma unroll
            for (int kj = 0; kj < 7; ++kj) d[kj] += __shfl_xor(d[kj], 2);
#pragma unroll
            for (int kj = 0; kj < 7; ++kj) d[kj] += rrow[kj];

            // group max (tree) + online rescale
            const float g01 = fmaxf(d[0], d[1]);
            const float g23 = fmaxf(d[2], d[3]);
            const float g45 = fmaxf(d[4], d[5]);
            const float gm  = fmaxf(fmaxf(g01, g23), fmaxf(g45, d[6]));
            const float mn  = fmaxf(m, gm);
            const float corr = __expf(m - mn);   // first iter: ~0
            m = mn;
            l *= corr;
#pragma unroll
            for (int e = 0; e < 8; ++e) o[e] *= corr;

#pragma unroll
            for (int kj = 0; kj < 7; ++kj) {
                const float pe = __expf(d[kj] - m);
                d[kj] = pe;
                l += pe;
            }

            // 7 independent V loads + PV accumulation
#pragma unroll
            for (int kj = 0; kj < 7; ++kj) {
                const int ix = sj + 2 * kj;
                const uint4 vv = *(const uint4*)(vhb + rowbase + (size_t)ix * 128);
                const float pe = d[kj];
                o[0] = fmaf(pe, uasf(vv.x << 16),          o[0]);
                o[1] = fmaf(pe, uasf(vv.x & 0xFFFF0000u),  o[1]);
                o[2] = fmaf(pe, uasf(vv.y << 16),          o[2]);
                o[3] = fmaf(pe, uasf(vv.y & 0xFFFF0000u),  o[3]);
                o[4] = fmaf(pe, uasf(vv.z << 16),          o[4]);
                o[5] = fmaf(pe, uasf(vv.z & 0xFFFF0000u),  o[5]);
                o[6] = fmaf(pe, uasf(vv.w << 16),          o[6]);
                o[7] = fmaf(pe, uasf(vv.w & 0xFFFF0000u),  o[7]);
            }
        }

        const float inv = 1.0f / l;
        bf16x8 ow;
#pragma unroll
        for (int e = 0; e < 8; ++e) ow[e] = bf16r(o[e] * inv);
        *(bf16x8*)&attS[p][coff] = ow;
    }

    __syncthreads();

    // ---------------- S3: out projection from LDS att tile ------------------
    {
        const int wv   = t >> 6;
        const int lane = t & 63;
        const int lr   = lane & 15;
        const int lg   = lane >> 4;
        const int col0 = wv * 32;
        const short* Wz = Wt + 3 * 16384;

        bf16x8 bfr[8];
#pragma unroll
        for (int nt = 0; nt < 2; ++nt) {
            const short* wrow = Wz + (col0 + nt * 16 + lr) * 128 + lg * 8;
#pragma unroll
            for (int kk = 0; kk < 4; ++kk)
                bfr[nt * 4 + kk] = *(const bf16x8*)(wrow + kk * 32);
        }
        bf16x8 a[4];
#pragma unroll
        for (int kk = 0; kk < 4; ++kk)
            a[kk] = *(const bf16x8*)&attS[lr][kk * 32 + lg * 8];

#pragma unroll
        for (int nt = 0; nt < 2; ++nt) {
            const int col = col0 + nt * 16 + lr;
            f32x4 acc = {0.f, 0.f, 0.f, 0.f};
#pragma unroll
            for (int kk = 0; kk < 4; ++kk)
                acc = __builtin_amdgcn_mfma_f32_16x16x32_bf16(a[kk], bfr[nt * 4 + kk], acc, 0, 0, 0);
            const float bc = bo[col];
#pragma unroll
            for (int jj = 0; jj < 4; ++jj)
                out[(size_t)(work * 16 + lg * 4 + jj) * 128 + col] = acc[jj] + bc;
        }
    }
}

// ---------------------------------------------------------------------------
extern "C" void kernel_launch(void* const* d_in, const int* in_sizes, int n_in,
                              void* d_out, int out_size, void* d_ws, size_t ws_size,
                              hipStream_t stream)
{
    const float* q   = (const float*)d_in[0];
    const float* k   = (const float*)d_in[1];
    const float* v   = (const float*)d_in[2];
    const float* Wq  = (const float*)d_in[3];
    const float* bq  = (const float*)d_in[4];
    const float* Wk  = (const float*)d_in[5];
    const float* bk  = (const float*)d_in[6];
    const float* Wv  = (const float*)d_in[7];
    const float* bv  = (const float*)d_in[8];
    const float* rpb = (const float*)d_in[9];
    const float* Wo  = (const float*)d_in[10];
    const float* bo  = (const float*)d_in[11];

    float* ws   = (float*)d_ws;
    float* qh   = ws;                                   // f32 [8192][128]  (4 MB)
    short* khb  = (short*)(ws + (size_t)NPIX * 128);    // bf16 [8192][128] (2 MB)
    short* vhb  = khb + (size_t)NPIX * 128;             // bf16 (2 MB)
    short* Wt   = vhb + (size_t)NPIX * 128;             // bf16 [4][128][128] (128 KB)
    float* out  = (float*)d_out;

    hipLaunchKernelGGL(prep_w, dim3(16), dim3(256), 0, stream, Wq, Wk, Wv, Wo, Wt);

    hipLaunchKernelGGL(qkv_mfma, dim3(256, 3), dim3(256), 0, stream,
                       q, k, v, Wt, bq, bk, bv, qh, khb, vhb);

    hipLaunchKernelGGL(natten_out, dim3(512), dim3(256), 0, stream,
                       qh, khb, vhb, rpb, Wt, bo, out);
}